// Round 8
// baseline (91.038 us; speedup 1.0000x reference)
//
#include <hip/hip_runtime.h>

typedef __attribute__((ext_vector_type(8))) short bf16x8;
typedef __attribute__((ext_vector_type(4))) float f32x4;
typedef unsigned short u16;

#define D_MODEL 1024
#define ROWS 64            // rows per block: grid 256, 1 block/CU, 16 waves

// Packed-weight geometry: fragments of 512 bf16 (64 lanes x 8), frag(nt,kt).
// Phase-1 B: 17 col-tiles (16 down + 1 gate-padded) x 32 k-tiles (K=1024).
// Phase-2 B: 64 col-tiles (N=1024)                x  8 k-tiles (K=256).
#define WD_FRAGS (17 * 32)
#define WU_FRAGS (64 * 8)
#define WD_ELEMS (WD_FRAGS * 512)   // 278528 bf16
#define WU_ELEMS (WU_FRAGS * 512)   // 262144 bf16

// LDS map (bytes), total 65536:
//  phase 1: buf0 [0,32768) | buf1 [32768,65536)  (x double-buffer)
//  gate:    g[64][4] f32 = [32768,33792)  (aliases buf1 head; buf1 dead after c=3)
//  phase 2: ds (gated-down, 64x512B) = buf0 [0,32768); epilogue stores direct.
#define LDS_TOTAL 65536

__device__ __forceinline__ u16 f2bf(float f) {  // RNE f32 -> bf16
  union { float f; unsigned u; } v; v.f = f;
  return (u16)((v.u + 0x7fffu + ((v.u >> 16) & 1u)) >> 16);
}

// Pack per-expert weights into MFMA B-fragment order (bf16).
// Fragment element (lane, j) holds B[k = kt*32 + (lane>>4)*8 + j][col = nt*16 + (lane&15)].
__global__ void lora_prep(const float* __restrict__ Wd, const float* __restrict__ Wu,
                          const float* __restrict__ Wg,
                          u16* __restrict__ wd_pack, u16* __restrict__ wu_pack) {
  int idx = blockIdx.x * 256 + threadIdx.x;
  if (idx < WD_ELEMS) {
    int frag = idx >> 9, w = idx & 511;
    int lane = w >> 3, j = w & 7;
    int nt = frag >> 5, kt = frag & 31;
    int k = kt * 32 + (lane >> 4) * 8 + j;        // 0..1023
    int col = nt * 16 + (lane & 15);              // 0..271
    float v;
    if (col < 256) {
      v = Wd[((col >> 6) * 1024 + k) * 64 + (col & 63)];   // W_down[e][k][a]
    } else {
      int c2 = col - 256;
      v = (c2 < 4) ? Wg[k * 4 + c2] : 0.f;                 // W_gate[k][e], zero-padded
    }
    wd_pack[idx] = f2bf(v);
  } else if (idx < WD_ELEMS + WU_ELEMS) {
    int u = idx - WD_ELEMS;
    int frag = u >> 9, w = u & 511;
    int lane = w >> 3, j = w & 7;
    int nt = frag >> 3, kt = frag & 7;
    int k = kt * 32 + (lane >> 4) * 8 + j;        // 0..255 (= e*64 + a)
    int col = nt * 16 + (lane & 15);              // 0..1023
    wu_pack[u] = f2bf(Wu[((k >> 6) * 64 + (k & 63)) * 1024 + col]);  // W_up[e][a][d]
  }
}

// LDS chunk tile: [64 rows][256 k] bf16, row stride 512 B, XOR-swizzled:
// byte = row*512 + (2*k ^ ((row&7)<<4))  -> ds_read_b128 A-frags are ~2-way (free).
__device__ __forceinline__ void pack_store(char* dst, int r, int col, float4 v0, float4 v1) {
  bf16x8 h;
  h[0] = (short)f2bf(v0.x); h[1] = (short)f2bf(v0.y);
  h[2] = (short)f2bf(v0.z); h[3] = (short)f2bf(v0.w);
  h[4] = (short)f2bf(v1.x); h[5] = (short)f2bf(v1.y);
  h[6] = (short)f2bf(v1.z); h[7] = (short)f2bf(v1.w);
  int cb = col * 2;
  *(bf16x8*)(dst + r * 512 + (cb ^ ((r & 7) << 4))) = h;
}

__global__ __launch_bounds__(1024, 4) void lora_main(
    const float* __restrict__ x, const float* __restrict__ b_gate,
    const u16* __restrict__ wd_pack, const u16* __restrict__ wu_pack,
    float* __restrict__ out) {
  extern __shared__ char smem[];
  float* g = (float*)(smem + 32768);   // aliases buf1 head (dead by gate time)

  const int tid = threadIdx.x;     // 0..1023
  const int lane = tid & 63;
  const int wave = tid >> 6;       // 0..15
  const int l15 = lane & 15;
  const int lg = lane >> 4;
  const size_t row0 = (size_t)blockIdx.x * ROWS;
  const float* xblk = x + row0 * D_MODEL;

  f32x4 acc[4];      // row-frags r=0..3; wave w owns down col-tile nt=w
  f32x4 accg[4];     // gate tile (nt=16), wave 15 only, all 4 row-frags (R1 pattern)
#pragma unroll
  for (int r = 0; r < 4; ++r) acc[r] = {0.f, 0.f, 0.f, 0.f};
#pragma unroll
  for (int r = 0; r < 4; ++r) accg[r] = {0.f, 0.f, 0.f, 0.f};

  // ---- prologue: stage K-chunk 0 into buf0 (fp32 -> bf16, swizzled)
#pragma unroll
  for (int it = 0; it < 2; ++it) {
    int flat = it * 8192 + tid * 8;          // 64 rows x 256 cols = 16384 floats
    int r = flat >> 8, col = flat & 255;
    float4 v0 = *(const float4*)(xblk + r * D_MODEL + col);
    float4 v1 = *(const float4*)(xblk + r * D_MODEL + col + 4);
    pack_store(smem, r, col, v0, v1);
  }
  __syncthreads();

  // ---- phase 1: down[64][256] (+gate logits), K = 1024 in 4 chunks of 256.
  // B fragments prefetched depth-2 (slot = ks % 3, static indices after unroll).
  float4 pre[4];
  bf16x8 bq[3];
  bf16x8 gq[3];
#pragma unroll 1
  for (int c = 0; c < 4; ++c) {
    if (c < 3) {  // T14 split: issue next chunk's global loads before compute
      const float* src = xblk + (c + 1) * 256;
#pragma unroll
      for (int it = 0; it < 2; ++it) {
        int flat = it * 8192 + tid * 8;
        int r = flat >> 8, col = flat & 255;
        pre[2 * it]     = *(const float4*)(src + r * D_MODEL + col);
        pre[2 * it + 1] = *(const float4*)(src + r * D_MODEL + col + 4);
      }
    }
    const char* buf = smem + (c & 1) * 32768;
    // preload B for ks = 0,1
#pragma unroll
    for (int pk = 0; pk < 2; ++pk) {
      int ktg = c * 8 + pk;
      bq[pk] = *(const bf16x8*)(wd_pack + (size_t)(wave * 32 + ktg) * 512 + lane * 8);
      if (wave == 15)
        gq[pk] = *(const bf16x8*)(wd_pack + (size_t)(512 + ktg) * 512 + lane * 8);
    }
#pragma unroll
    for (int ks = 0; ks < 8; ++ks) {
      const int s = ks % 3;
      if (ks < 6) {  // prefetch ks+2
        int ktg2 = c * 8 + ks + 2;
        int s2 = (ks + 2) % 3;
        bq[s2] = *(const bf16x8*)(wd_pack + (size_t)(wave * 32 + ktg2) * 512 + lane * 8);
        if (wave == 15)
          gq[s2] = *(const bf16x8*)(wd_pack + (size_t)(512 + ktg2) * 512 + lane * 8);
      }
      bf16x8 a[4];
#pragma unroll
      for (int r = 0; r < 4; ++r) {
        int rr = r * 16 + l15;
        int cb = (ks * 32 + lg * 8) * 2;
        a[r] = *(const bf16x8*)(buf + rr * 512 + (cb ^ ((rr & 7) << 4)));
      }
#pragma unroll
      for (int r = 0; r < 4; ++r)
        acc[r] = __builtin_amdgcn_mfma_f32_16x16x32_bf16(a[r], bq[s], acc[r], 0, 0, 0);
      if (wave == 15) {  // gate tile: all 4 row-frags on one wave (R1-proven)
#pragma unroll
        for (int r = 0; r < 4; ++r)
          accg[r] = __builtin_amdgcn_mfma_f32_16x16x32_bf16(a[r], gq[s], accg[r], 0, 0, 0);
      }
    }
    if (c < 3) {  // write-late: convert + ds_write into the other buffer
      char* dst = smem + ((c + 1) & 1) * 32768;
#pragma unroll
      for (int it = 0; it < 2; ++it) {
        int flat = it * 8192 + tid * 8;
        int r = flat >> 8, col = flat & 255;
        pack_store(dst, r, col, pre[2 * it], pre[2 * it + 1]);
      }
    }
    __syncthreads();
  }

  // ---- gate logits -> g (buf1 head; buf1 x-data dead after the last barrier).
  // C-layout: col=lane&15, row=(lane>>4)*4+reg.  (R1's exact pattern, wave 15)
  if (wave == 15 && l15 < 4) {
#pragma unroll
    for (int r = 0; r < 4; ++r)
#pragma unroll
      for (int j = 0; j < 4; ++j)
        g[(r * 16 + lg * 4 + j) * 4 + l15] = accg[r][j];
  }
  __syncthreads();
  if (tid < ROWS) {
    float v0 = g[tid * 4 + 0] + b_gate[0];
    float v1 = g[tid * 4 + 1] + b_gate[1];
    float v2 = g[tid * 4 + 2] + b_gate[2];
    float v3 = g[tid * 4 + 3] + b_gate[3];
    float m = fmaxf(fmaxf(v0, v1), fmaxf(v2, v3));
    float e0 = expf(v0 - m), e1 = expf(v1 - m), e2 = expf(v2 - m), e3 = expf(v3 - m);
    float inv = 1.f / (e0 + e1 + e2 + e3);
    g[tid * 4 + 0] = e0 * inv; g[tid * 4 + 1] = e1 * inv;
    g[tid * 4 + 2] = e2 * inv; g[tid * 4 + 3] = e3 * inv;
  }
  __syncthreads();

  // ---- apply gate, pack down to bf16 into buf0 (same swizzled layout, k=e*64+a)
  char* ds = smem;
  {
    int col = wave * 16 + l15;    // wave w owns col-tile w
    int e = wave >> 2;            // 4 col-tiles per expert
    int cb = col * 2;
#pragma unroll
    for (int r = 0; r < 4; ++r) {
#pragma unroll
      for (int j = 0; j < 4; ++j) {
        int row = r * 16 + lg * 4 + j;
        float val = acc[r][j] * g[row * 4 + e];
        *(u16*)(ds + row * 512 + (cb ^ ((row & 7) << 4))) = f2bf(val);
      }
    }
  }
  __syncthreads();

  // ---- phase 2: out[64][1024] = down_g[64][256] @ Wup, N in 4 chunks of 256.
  // Per nc: wave w owns col-tile nc*16+w. Direct global stores (R1-proven).
  bf16x8 b2[3];
#pragma unroll 1
  for (int nc = 0; nc < 4; ++nc) {
    f32x4 acc2[4];
#pragma unroll
    for (int r = 0; r < 4; ++r) acc2[r] = {0.f, 0.f, 0.f, 0.f};
    // preload B for ks = 0,1
#pragma unroll
    for (int pk = 0; pk < 2; ++pk)
      b2[pk] = *(const bf16x8*)(wu_pack + (size_t)((nc * 16 + wave) * 8 + pk) * 512 + lane * 8);
#pragma unroll
    for (int ks = 0; ks < 8; ++ks) {
      const int s = ks % 3;
      if (ks < 6) {  // prefetch ks+2
        int s2 = (ks + 2) % 3;
        b2[s2] = *(const bf16x8*)(wu_pack + (size_t)((nc * 16 + wave) * 8 + ks + 2) * 512 + lane * 8);
      }
      bf16x8 a[4];
#pragma unroll
      for (int r = 0; r < 4; ++r) {
        int rr = r * 16 + l15;
        int cb = (ks * 32 + lg * 8) * 2;
        a[r] = *(const bf16x8*)(ds + rr * 512 + (cb ^ ((rr & 7) << 4)));
      }
#pragma unroll
      for (int r = 0; r < 4; ++r)
        acc2[r] = __builtin_amdgcn_mfma_f32_16x16x32_bf16(a[r], b2[s], acc2[r], 0, 0, 0);
    }
    {
      int colg = nc * 256 + wave * 16 + l15;
#pragma unroll
      for (int r = 0; r < 4; ++r)
#pragma unroll
        for (int j = 0; j < 4; ++j) {
          int row = r * 16 + lg * 4 + j;
          out[(row0 + row) * D_MODEL + colg] = acc2[r][j];
        }
    }
  }
}

extern "C" void kernel_launch(void* const* d_in, const int* in_sizes, int n_in,
                              void* d_out, int out_size, void* d_ws, size_t ws_size,
                              hipStream_t stream) {
  const float* x  = (const float*)d_in[0];
  const float* Wd = (const float*)d_in[1];
  const float* Wu = (const float*)d_in[2];
  const float* Wg = (const float*)d_in[3];
  const float* bg = (const float*)d_in[4];
  float* out = (float*)d_out;
  const int M = in_sizes[0] / D_MODEL;  // 16384

  u16* wd_pack = (u16*)d_ws;            // 557056 B
  u16* wu_pack = wd_pack + WD_ELEMS;    // +524288 B  (needs ~1.03 MB of ws)

  const int total = WD_ELEMS + WU_ELEMS;
  lora_prep<<<(total + 255) / 256, 256, 0, stream>>>(Wd, Wu, Wg, wd_pack, wu_pack);
  lora_main<<<M / ROWS, 1024, LDS_TOTAL, stream>>>(x, bg, wd_pack, wu_pack, out);
}

// Round 9
// 71.482 us; speedup vs baseline: 1.2736x; 1.2736x over previous
//
#include <hip/hip_runtime.h>

typedef __attribute__((ext_vector_type(8))) short bf16x8;
typedef __attribute__((ext_vector_type(4))) float f32x4;
typedef unsigned short u16;

#define D_MODEL 1024
#define ROWS 32            // rows per block: grid 512, 2 blocks/CU, 16 waves each

// Packed-weight geometry: fragments of 512 bf16 (64 lanes x 8), frag(nt,kt).
// Phase-1 B: 17 col-tiles (16 down + 1 gate-padded) x 32 k-tiles (K=1024).
// Phase-2 B: 64 col-tiles (N=1024)                x  8 k-tiles (K=256).
#define WD_FRAGS (17 * 32)
#define WU_FRAGS (64 * 8)
#define WD_ELEMS (WD_FRAGS * 512)   // 278528 bf16
#define WU_ELEMS (WU_FRAGS * 512)   // 262144 bf16

// LDS map (bytes), total 49664 (x2 blocks/CU = 99328 <= 160K):
//  phase 1: buf0 [0,16384) | buf1 [16384,32768) | g[32][4] f32 [32768,33280)
//  phase 2: ds (gated-down, 32x512B) = buf0 [0,16384)
//           tb (transpose, 32x260 f32 = 33280 B) = [16384,49664)  (buf1+g dead)
#define LDS_TOTAL 49664
#define TB_STRIDE 260

__device__ __forceinline__ u16 f2bf(float f) {  // RNE f32 -> bf16
  union { float f; unsigned u; } v; v.f = f;
  return (u16)((v.u + 0x7fffu + ((v.u >> 16) & 1u)) >> 16);
}

// Pack per-expert weights into MFMA B-fragment order (bf16).
// Fragment element (lane, j) holds B[k = kt*32 + (lane>>4)*8 + j][col = nt*16 + (lane&15)].
__global__ void lora_prep(const float* __restrict__ Wd, const float* __restrict__ Wu,
                          const float* __restrict__ Wg,
                          u16* __restrict__ wd_pack, u16* __restrict__ wu_pack) {
  int idx = blockIdx.x * 256 + threadIdx.x;
  if (idx < WD_ELEMS) {
    int frag = idx >> 9, w = idx & 511;
    int lane = w >> 3, j = w & 7;
    int nt = frag >> 5, kt = frag & 31;
    int k = kt * 32 + (lane >> 4) * 8 + j;        // 0..1023
    int col = nt * 16 + (lane & 15);              // 0..271
    float v;
    if (col < 256) {
      v = Wd[((col >> 6) * 1024 + k) * 64 + (col & 63)];   // W_down[e][k][a]
    } else {
      int c2 = col - 256;
      v = (c2 < 4) ? Wg[k * 4 + c2] : 0.f;                 // W_gate[k][e], zero-padded
    }
    wd_pack[idx] = f2bf(v);
  } else if (idx < WD_ELEMS + WU_ELEMS) {
    int u = idx - WD_ELEMS;
    int frag = u >> 9, w = u & 511;
    int lane = w >> 3, j = w & 7;
    int nt = frag >> 3, kt = frag & 7;
    int k = kt * 32 + (lane >> 4) * 8 + j;        // 0..255 (= e*64 + a)
    int col = nt * 16 + (lane & 15);              // 0..1023
    wu_pack[u] = f2bf(Wu[((k >> 6) * 64 + (k & 63)) * 1024 + col]);  // W_up[e][a][d]
  }
}

// LDS chunk tile: [32 rows][256 k] bf16, row stride 512 B, XOR-swizzled:
// byte = row*512 + (2*k ^ ((row&7)<<4))  -> ds_read_b128 A-frags are ~2-way (free).
__device__ __forceinline__ void pack_store(char* dst, int r, int col, float4 v0, float4 v1) {
  bf16x8 h;
  h[0] = (short)f2bf(v0.x); h[1] = (short)f2bf(v0.y);
  h[2] = (short)f2bf(v0.z); h[3] = (short)f2bf(v0.w);
  h[4] = (short)f2bf(v1.x); h[5] = (short)f2bf(v1.y);
  h[6] = (short)f2bf(v1.z); h[7] = (short)f2bf(v1.w);
  int cb = col * 2;
  *(bf16x8*)(dst + r * 512 + (cb ^ ((r & 7) << 4))) = h;
}

__global__ __launch_bounds__(1024, 8) void lora_main(
    const float* __restrict__ x, const float* __restrict__ b_gate,
    const u16* __restrict__ wd_pack, const u16* __restrict__ wu_pack,
    float* __restrict__ out) {
  extern __shared__ char smem[];
  float* g = (float*)(smem + 32768);

  const int tid = threadIdx.x;     // 0..1023
  const int lane = tid & 63;
  const int wave = tid >> 6;       // 0..15
  const int l15 = lane & 15;
  const int lg = lane >> 4;
  const size_t row0 = (size_t)blockIdx.x * ROWS;
  const float* xblk = x + row0 * D_MODEL;

  f32x4 acc[2];      // row-frags r=0..1; wave w owns down col-tile nt=w
  f32x4 accg[2];     // gate tile (nt=16), wave 15 only (R8-proven single-wave gate)
#pragma unroll
  for (int r = 0; r < 2; ++r) acc[r] = {0.f, 0.f, 0.f, 0.f};
#pragma unroll
  for (int r = 0; r < 2; ++r) accg[r] = {0.f, 0.f, 0.f, 0.f};

  // ---- prologue: stage K-chunk 0 into buf0 (fp32 -> bf16, swizzled)
  {
    int flat = tid * 8;                      // 32 rows x 256 cols = 8192 floats
    int r = flat >> 8, col = flat & 255;
    float4 v0 = *(const float4*)(xblk + r * D_MODEL + col);
    float4 v1 = *(const float4*)(xblk + r * D_MODEL + col + 4);
    pack_store(smem, r, col, v0, v1);
  }
  __syncthreads();

  // ---- phase 1: down[32][256] (+gate logits), K = 1024 in 4 chunks of 256.
  // B fragments prefetched depth-2 (bq slot = ks % 3); gate gq depth-1 ping-pong
  // (wave 15 only) to keep VGPR <= 64 for 8 waves/SIMD.
  float4 pre[2];
  bf16x8 bq[3];
  bf16x8 gq[2];
#pragma unroll 1
  for (int c = 0; c < 4; ++c) {
    if (c < 3) {  // T14 split: issue next chunk's global loads before compute
      const float* src = xblk + (c + 1) * 256;
      int flat = tid * 8;
      int r = flat >> 8, col = flat & 255;
      pre[0] = *(const float4*)(src + r * D_MODEL + col);
      pre[1] = *(const float4*)(src + r * D_MODEL + col + 4);
    }
    const char* buf = smem + (c & 1) * 16384;
    // preload bq for ks = 0,1; gq for ks = 0
#pragma unroll
    for (int pk = 0; pk < 2; ++pk)
      bq[pk] = *(const bf16x8*)(wd_pack + (size_t)(wave * 32 + c * 8 + pk) * 512 + lane * 8);
    if (wave == 15)
      gq[0] = *(const bf16x8*)(wd_pack + (size_t)(512 + c * 8) * 512 + lane * 8);
#pragma unroll
    for (int ks = 0; ks < 8; ++ks) {
      const int s = ks % 3;
      if (ks < 6) {  // prefetch bq for ks+2
        int s2 = (ks + 2) % 3;
        bq[s2] = *(const bf16x8*)(wd_pack + (size_t)(wave * 32 + c * 8 + ks + 2) * 512 + lane * 8);
      }
      if (wave == 15 && ks < 7)  // prefetch gq for ks+1
        gq[(ks + 1) & 1] = *(const bf16x8*)(wd_pack + (size_t)(512 + c * 8 + ks + 1) * 512 + lane * 8);
      bf16x8 a[2];
#pragma unroll
      for (int r = 0; r < 2; ++r) {
        int rr = r * 16 + l15;
        int cb = (ks * 32 + lg * 8) * 2;
        a[r] = *(const bf16x8*)(buf + rr * 512 + (cb ^ ((rr & 7) << 4)));
      }
#pragma unroll
      for (int r = 0; r < 2; ++r)
        acc[r] = __builtin_amdgcn_mfma_f32_16x16x32_bf16(a[r], bq[s], acc[r], 0, 0, 0);
      if (wave == 15) {  // gate tile: both row-frags on one wave (R8-proven)
#pragma unroll
        for (int r = 0; r < 2; ++r)
          accg[r] = __builtin_amdgcn_mfma_f32_16x16x32_bf16(a[r], gq[ks & 1], accg[r], 0, 0, 0);
      }
    }
    if (c < 3) {  // write-late: convert + ds_write into the other buffer
      char* dst = smem + ((c + 1) & 1) * 16384;
      int flat = tid * 8;
      int r = flat >> 8, col = flat & 255;
      pack_store(dst, r, col, pre[0], pre[1]);
    }
    __syncthreads();
  }

  // ---- gate logits -> g. C-layout: col=lane&15, row=(lane>>4)*4+reg. (R8 pattern)
  if (wave == 15 && l15 < 4) {
#pragma unroll
    for (int r = 0; r < 2; ++r)
#pragma unroll
      for (int j = 0; j < 4; ++j)
        g[(r * 16 + lg * 4 + j) * 4 + l15] = accg[r][j];
  }
  __syncthreads();
  if (tid < ROWS) {
    float v0 = g[tid * 4 + 0] + b_gate[0];
    float v1 = g[tid * 4 + 1] + b_gate[1];
    float v2 = g[tid * 4 + 2] + b_gate[2];
    float v3 = g[tid * 4 + 3] + b_gate[3];
    float m = fmaxf(fmaxf(v0, v1), fmaxf(v2, v3));
    float e0 = expf(v0 - m), e1 = expf(v1 - m), e2 = expf(v2 - m), e3 = expf(v3 - m);
    float inv = 1.f / (e0 + e1 + e2 + e3);
    g[tid * 4 + 0] = e0 * inv; g[tid * 4 + 1] = e1 * inv;
    g[tid * 4 + 2] = e2 * inv; g[tid * 4 + 3] = e3 * inv;
  }
  __syncthreads();

  // ---- apply gate, pack down to bf16 into buf0 (same swizzled layout, k=e*64+a)
  char* ds = smem;
  {
    int col = wave * 16 + l15;    // wave w owns col-tile w
    int e = wave >> 2;            // 4 col-tiles per expert
    int cb = col * 2;
#pragma unroll
    for (int r = 0; r < 2; ++r) {
#pragma unroll
      for (int j = 0; j < 4; ++j) {
        int row = r * 16 + lg * 4 + j;
        float val = acc[r][j] * g[row * 4 + e];
        *(u16*)(ds + row * 512 + (cb ^ ((row & 7) << 4))) = f2bf(val);
      }
    }
  }
  __syncthreads();

  // ---- phase 2: out[32][1024] = down_g[32][256] @ Wup, N in 4 chunks of 256.
  // Per nc: wave w owns col-tile nc*16+w. Epilogue through tb (TB_STRIDE 260,
  // R4/R5-proven) for contiguous float4 stores; tb aliases buf1+g (dead).
  float* tb = (float*)(smem + 16384);
  bf16x8 b2[3];
#pragma unroll 1
  for (int nc = 0; nc < 4; ++nc) {
    f32x4 acc2[2];
#pragma unroll
    for (int r = 0; r < 2; ++r) acc2[r] = {0.f, 0.f, 0.f, 0.f};
    // preload B for ks = 0,1
#pragma unroll
    for (int pk = 0; pk < 2; ++pk)
      b2[pk] = *(const bf16x8*)(wu_pack + (size_t)((nc * 16 + wave) * 8 + pk) * 512 + lane * 8);
#pragma unroll
    for (int ks = 0; ks < 8; ++ks) {
      const int s = ks % 3;
      if (ks < 6) {  // prefetch ks+2
        int s2 = (ks + 2) % 3;
        b2[s2] = *(const bf16x8*)(wu_pack + (size_t)((nc * 16 + wave) * 8 + ks + 2) * 512 + lane * 8);
      }
      bf16x8 a[2];
#pragma unroll
      for (int r = 0; r < 2; ++r) {
        int rr = r * 16 + l15;
        int cb = (ks * 32 + lg * 8) * 2;
        a[r] = *(const bf16x8*)(ds + rr * 512 + (cb ^ ((rr & 7) << 4)));
      }
#pragma unroll
      for (int r = 0; r < 2; ++r)
        acc2[r] = __builtin_amdgcn_mfma_f32_16x16x32_bf16(a[r], b2[s], acc2[r], 0, 0, 0);
    }
    {
      int cl = wave * 16 + l15;           // col within this 256-col chunk
#pragma unroll
      for (int r = 0; r < 2; ++r)
#pragma unroll
        for (int j = 0; j < 4; ++j)
          tb[(r * 16 + lg * 4 + j) * TB_STRIDE + cl] = acc2[r][j];
    }
    __syncthreads();
#pragma unroll
    for (int it = 0; it < 2; ++it) {
      int flat = it * 4096 + tid * 4;     // 32 rows x 256 cols f32
      int row = flat >> 8, col = flat & 255;
      float4 v = *(const float4*)(tb + row * TB_STRIDE + col);
      *(float4*)(out + (row0 + row) * D_MODEL + nc * 256 + col) = v;
    }
    __syncthreads();
  }
}

extern "C" void kernel_launch(void* const* d_in, const int* in_sizes, int n_in,
                              void* d_out, int out_size, void* d_ws, size_t ws_size,
                              hipStream_t stream) {
  const float* x  = (const float*)d_in[0];
  const float* Wd = (const float*)d_in[1];
  const float* Wu = (const float*)d_in[2];
  const float* Wg = (const float*)d_in[3];
  const float* bg = (const float*)d_in[4];
  float* out = (float*)d_out;
  const int M = in_sizes[0] / D_MODEL;  // 16384

  u16* wd_pack = (u16*)d_ws;            // 557056 B
  u16* wu_pack = wd_pack + WD_ELEMS;    // +524288 B  (needs ~1.03 MB of ws)

  const int total = WD_ELEMS + WU_ELEMS;
  lora_prep<<<(total + 255) / 256, 256, 0, stream>>>(Wd, Wu, Wg, wd_pack, wu_pack);
  lora_main<<<M / ROWS, 1024, LDS_TOTAL, stream>>>(x, bg, wd_pack, wu_pack, out);
}

// Round 10
// 56.106 us; speedup vs baseline: 1.6226x; 1.2741x over previous
//
#include <hip/hip_runtime.h>

typedef __attribute__((ext_vector_type(8))) short bf16x8;
typedef __attribute__((ext_vector_type(4))) float f32x4;
typedef unsigned short u16;

#define D_MODEL 1024
#define ROWS 32            // rows per block: grid 512, 2 blocks/CU, 8 waves each

// Packed-weight geometry: fragments of 512 bf16 (64 lanes x 8), frag(nt,kt).
// Phase-1 B: 17 col-tiles (16 down + 1 gate-padded) x 32 k-tiles (K=1024).
// Phase-2 B: 64 col-tiles (N=1024)                x  8 k-tiles (K=256).
#define WD_FRAGS (17 * 32)
#define WU_FRAGS (64 * 8)
#define WD_ELEMS (WD_FRAGS * 512)   // 278528 bf16
#define WU_ELEMS (WU_FRAGS * 512)   // 262144 bf16

// LDS map (bytes), total 49664:
//  phase 1: buf0 [0,16384) | buf1 [16384,32768) | g[32][4] f32 [32768,33280)
//  phase 2: ds (gated-down, 32x512B) = buf0 [0,16384)
//           tb (transpose, 32x260 f32 = 33280 B) = [16384,49664)  (buf1+g dead)
#define LDS_TOTAL 49664
#define TB_STRIDE 260

__device__ __forceinline__ u16 f2bf(float f) {  // RNE f32 -> bf16
  union { float f; unsigned u; } v; v.f = f;
  return (u16)((v.u + 0x7fffu + ((v.u >> 16) & 1u)) >> 16);
}

// Pack per-expert weights into MFMA B-fragment order (bf16).
// Fragment element (lane, j) holds B[k = kt*32 + (lane>>4)*8 + j][col = nt*16 + (lane&15)].
__global__ void lora_prep(const float* __restrict__ Wd, const float* __restrict__ Wu,
                          const float* __restrict__ Wg,
                          u16* __restrict__ wd_pack, u16* __restrict__ wu_pack) {
  int idx = blockIdx.x * 256 + threadIdx.x;
  if (idx < WD_ELEMS) {
    int frag = idx >> 9, w = idx & 511;
    int lane = w >> 3, j = w & 7;
    int nt = frag >> 5, kt = frag & 31;
    int k = kt * 32 + (lane >> 4) * 8 + j;        // 0..1023
    int col = nt * 16 + (lane & 15);              // 0..271
    float v;
    if (col < 256) {
      v = Wd[((col >> 6) * 1024 + k) * 64 + (col & 63)];   // W_down[e][k][a]
    } else {
      int c2 = col - 256;
      v = (c2 < 4) ? Wg[k * 4 + c2] : 0.f;                 // W_gate[k][e], zero-padded
    }
    wd_pack[idx] = f2bf(v);
  } else if (idx < WD_ELEMS + WU_ELEMS) {
    int u = idx - WD_ELEMS;
    int frag = u >> 9, w = u & 511;
    int lane = w >> 3, j = w & 7;
    int nt = frag >> 3, kt = frag & 7;
    int k = kt * 32 + (lane >> 4) * 8 + j;        // 0..255 (= e*64 + a)
    int col = nt * 16 + (lane & 15);              // 0..1023
    wu_pack[u] = f2bf(Wu[((k >> 6) * 64 + (k & 63)) * 1024 + col]);  // W_up[e][a][d]
  }
}

// LDS chunk tile: [32 rows][256 k] bf16, row stride 512 B, XOR-swizzled:
// byte = row*512 + (2*k ^ ((row&7)<<4))  -> ds_read_b128 A-frags are ~2-way (free).
__device__ __forceinline__ void pack_store(char* dst, int r, int col, float4 v0, float4 v1) {
  bf16x8 h;
  h[0] = (short)f2bf(v0.x); h[1] = (short)f2bf(v0.y);
  h[2] = (short)f2bf(v0.z); h[3] = (short)f2bf(v0.w);
  h[4] = (short)f2bf(v1.x); h[5] = (short)f2bf(v1.y);
  h[6] = (short)f2bf(v1.z); h[7] = (short)f2bf(v1.w);
  int cb = col * 2;
  *(bf16x8*)(dst + r * 512 + (cb ^ ((r & 7) << 4))) = h;
}

__device__ __forceinline__ bf16x8 ldsA(const char* buf, int r, int l15, int lg, int ks) {
  int rr = r * 16 + l15;
  int cb = (ks * 32 + lg * 8) * 2;
  return *(const bf16x8*)(buf + rr * 512 + (cb ^ ((rr & 7) << 4)));
}

__global__ __launch_bounds__(512, 4) void lora_main(
    const float* __restrict__ x, const float* __restrict__ b_gate,
    const u16* __restrict__ wd_pack, const u16* __restrict__ wu_pack,
    float* __restrict__ out) {
  extern __shared__ char smem[];
  float* g = (float*)(smem + 32768);

  const int tid = threadIdx.x;     // 0..511
  const int lane = tid & 63;
  const int wave = tid >> 6;       // 0..7
  const int l15 = lane & 15;
  const int lg = lane >> 4;
  const size_t row0 = (size_t)blockIdx.x * ROWS;
  const float* xblk = x + row0 * D_MODEL;

  f32x4 acc[2][2];   // [col-tile i][row-frag r]; wave w owns tiles {w, w+8}
  f32x4 accg[2];     // gate tile (nt=16), wave 7 only
#pragma unroll
  for (int i = 0; i < 2; ++i)
#pragma unroll
    for (int r = 0; r < 2; ++r) acc[i][r] = {0.f, 0.f, 0.f, 0.f};
#pragma unroll
  for (int r = 0; r < 2; ++r) accg[r] = {0.f, 0.f, 0.f, 0.f};

  // ---- prologue: stage K-chunk 0 into buf0 (fp32 -> bf16, swizzled)
#pragma unroll
  for (int it = 0; it < 2; ++it) {
    int flat = it * 4096 + tid * 8;          // 32 rows x 256 cols = 8192 floats
    int r = flat >> 8, col = flat & 255;
    float4 v0 = *(const float4*)(xblk + r * D_MODEL + col);
    float4 v1 = *(const float4*)(xblk + r * D_MODEL + col + 4);
    pack_store(smem, r, col, v0, v1);
  }
  __syncthreads();

  // ---- phase 1: down[32][256] (+gate logits), K = 1024 in 4 chunks of 256.
  // B fragments: ring-4, depth-3 prefetch. A fragments: ping-pong, depth-1.
  float4 pre[4];
  bf16x8 bq[4][2];
  bf16x8 gq[3];
  bf16x8 av[2][2];   // [ping][row-frag]
#pragma unroll 1
  for (int c = 0; c < 4; ++c) {
    if (c < 3) {  // T14 split: issue next chunk's global loads before compute
      const float* src = xblk + (c + 1) * 256;
#pragma unroll
      for (int it = 0; it < 2; ++it) {
        int flat = it * 4096 + tid * 8;
        int r = flat >> 8, col = flat & 255;
        pre[2 * it]     = *(const float4*)(src + r * D_MODEL + col);
        pre[2 * it + 1] = *(const float4*)(src + r * D_MODEL + col + 4);
      }
    }
    const char* buf = smem + (c & 1) * 16384;
    // preload B for ks = 0,1,2 (depth 3); gate gq for ks = 0,1 (depth 2)
#pragma unroll
    for (int pk = 0; pk < 3; ++pk) {
      int ktg = c * 8 + pk;
#pragma unroll
      for (int i = 0; i < 2; ++i)
        bq[pk][i] = *(const bf16x8*)(wd_pack + (size_t)((wave + i * 8) * 32 + ktg) * 512 + lane * 8);
    }
    if (wave == 7) {
      gq[0] = *(const bf16x8*)(wd_pack + (size_t)(512 + c * 8 + 0) * 512 + lane * 8);
      gq[1] = *(const bf16x8*)(wd_pack + (size_t)(512 + c * 8 + 1) * 512 + lane * 8);
    }
    // preload A for ks = 0
#pragma unroll
    for (int r = 0; r < 2; ++r) av[0][r] = ldsA(buf, r, l15, lg, 0);
#pragma unroll
    for (int ks = 0; ks < 8; ++ks) {
      const int s = ks & 3;
      const int p = ks & 1;
      if (ks < 5) {  // prefetch B for ks+3
        int ktg3 = c * 8 + ks + 3;
#pragma unroll
        for (int i = 0; i < 2; ++i)
          bq[(ks + 3) & 3][i] = *(const bf16x8*)(wd_pack + (size_t)((wave + i * 8) * 32 + ktg3) * 512 + lane * 8);
      }
      if (wave == 7 && ks < 6)  // prefetch gate for ks+2
        gq[(ks + 2) % 3] = *(const bf16x8*)(wd_pack + (size_t)(512 + c * 8 + ks + 2) * 512 + lane * 8);
      if (ks < 7) {  // prefetch A for ks+1
#pragma unroll
        for (int r = 0; r < 2; ++r) av[p ^ 1][r] = ldsA(buf, r, l15, lg, ks + 1);
      }
#pragma unroll
      for (int i = 0; i < 2; ++i)
#pragma unroll
        for (int r = 0; r < 2; ++r)
          acc[i][r] = __builtin_amdgcn_mfma_f32_16x16x32_bf16(av[p][r], bq[s][i], acc[i][r], 0, 0, 0);
      if (wave == 7) {
#pragma unroll
        for (int r = 0; r < 2; ++r)
          accg[r] = __builtin_amdgcn_mfma_f32_16x16x32_bf16(av[p][r], gq[ks % 3], accg[r], 0, 0, 0);
      }
    }
    if (c < 3) {  // write-late: convert + ds_write into the other buffer
      char* dst = smem + ((c + 1) & 1) * 16384;
#pragma unroll
      for (int it = 0; it < 2; ++it) {
        int flat = it * 4096 + tid * 8;
        int r = flat >> 8, col = flat & 255;
        pack_store(dst, r, col, pre[2 * it], pre[2 * it + 1]);
      }
    }
    __syncthreads();
  }

  // ---- gate softmax (fp32). C-layout: col=lane&15, row=(lane>>4)*4+reg.
  if (wave == 7 && l15 < 4) {
#pragma unroll
    for (int r = 0; r < 2; ++r)
#pragma unroll
      for (int j = 0; j < 4; ++j)
        g[(r * 16 + lg * 4 + j) * 4 + l15] = accg[r][j];
  }
  __syncthreads();
  if (tid < ROWS) {
    float v0 = g[tid * 4 + 0] + b_gate[0];
    float v1 = g[tid * 4 + 1] + b_gate[1];
    float v2 = g[tid * 4 + 2] + b_gate[2];
    float v3 = g[tid * 4 + 3] + b_gate[3];
    float m = fmaxf(fmaxf(v0, v1), fmaxf(v2, v3));
    float e0 = expf(v0 - m), e1 = expf(v1 - m), e2 = expf(v2 - m), e3 = expf(v3 - m);
    float inv = 1.f / (e0 + e1 + e2 + e3);
    g[tid * 4 + 0] = e0 * inv; g[tid * 4 + 1] = e1 * inv;
    g[tid * 4 + 2] = e2 * inv; g[tid * 4 + 3] = e3 * inv;
  }
  __syncthreads();

  // ---- apply gate, pack down to bf16 into buf0 (same swizzled layout, k=e*64+a)
  char* ds = smem;
#pragma unroll
  for (int i = 0; i < 2; ++i) {
    int nt = wave + i * 8;
    int col = nt * 16 + l15;
    int e = nt >> 2;              // 4 col-tiles per expert
    int cb = col * 2;
#pragma unroll
    for (int r = 0; r < 2; ++r) {
#pragma unroll
      for (int j = 0; j < 4; ++j) {
        int row = r * 16 + lg * 4 + j;
        float val = acc[i][r][j] * g[row * 4 + e];
        *(u16*)(ds + row * 512 + (cb ^ ((row & 7) << 4))) = f2bf(val);
      }
    }
  }
  __syncthreads();

  // ---- phase 2: out[32][1024] = down_g[32][256] @ Wup, N in 4 chunks of 256.
  // Epilogue transposes through tb (aliases buf1+g, both dead; DISJOINT from ds)
  // so each wave stores contiguous 1 KB float4 runs.
  float* tb = (float*)(smem + 16384);
  bf16x8 b2[4][2];
#pragma unroll 1
  for (int nc = 0; nc < 4; ++nc) {
    f32x4 acc2[2][2];
#pragma unroll
    for (int i = 0; i < 2; ++i)
#pragma unroll
      for (int r = 0; r < 2; ++r) acc2[i][r] = {0.f, 0.f, 0.f, 0.f};
    // preload B for ks = 0,1,2 (depth 3)
#pragma unroll
    for (int pk = 0; pk < 3; ++pk)
#pragma unroll
      for (int i = 0; i < 2; ++i)
        b2[pk][i] = *(const bf16x8*)(wu_pack + (size_t)((nc * 16 + wave * 2 + i) * 8 + pk) * 512 + lane * 8);
    // preload A for ks = 0
#pragma unroll
    for (int r = 0; r < 2; ++r) av[0][r] = ldsA(ds, r, l15, lg, 0);
#pragma unroll
    for (int ks = 0; ks < 8; ++ks) {
      const int s = ks & 3;
      const int p = ks & 1;
      if (ks < 5) {  // prefetch B for ks+3
#pragma unroll
        for (int i = 0; i < 2; ++i)
          b2[(ks + 3) & 3][i] = *(const bf16x8*)(wu_pack + (size_t)((nc * 16 + wave * 2 + i) * 8 + ks + 3) * 512 + lane * 8);
      }
      if (ks < 7) {  // prefetch A for ks+1
#pragma unroll
        for (int r = 0; r < 2; ++r) av[p ^ 1][r] = ldsA(ds, r, l15, lg, ks + 1);
      }
#pragma unroll
      for (int i = 0; i < 2; ++i)
#pragma unroll
        for (int r = 0; r < 2; ++r)
          acc2[i][r] = __builtin_amdgcn_mfma_f32_16x16x32_bf16(av[p][r], b2[s][i], acc2[i][r], 0, 0, 0);
    }
#pragma unroll
    for (int i = 0; i < 2; ++i) {
      int cl = wave * 32 + i * 16 + l15;    // col within this 256-col chunk
#pragma unroll
      for (int r = 0; r < 2; ++r)
#pragma unroll
        for (int j = 0; j < 4; ++j)
          tb[(r * 16 + lg * 4 + j) * TB_STRIDE + cl] = acc2[i][r][j];
    }
    __syncthreads();
#pragma unroll
    for (int it = 0; it < 4; ++it) {
      int flat = it * 2048 + tid * 4;       // 32 rows x 256 cols f32
      int row = flat >> 8, col = flat & 255;
      float4 v = *(const float4*)(tb + row * TB_STRIDE + col);
      *(float4*)(out + (row0 + row) * D_MODEL + nc * 256 + col) = v;
    }
    __syncthreads();
  }
}

extern "C" void kernel_launch(void* const* d_in, const int* in_sizes, int n_in,
                              void* d_out, int out_size, void* d_ws, size_t ws_size,
                              hipStream_t stream) {
  const float* x  = (const float*)d_in[0];
  const float* Wd = (const float*)d_in[1];
  const float* Wu = (const float*)d_in[2];
  const float* Wg = (const float*)d_in[3];
  const float* bg = (const float*)d_in[4];
  float* out = (float*)d_out;
  const int M = in_sizes[0] / D_MODEL;  // 16384

  u16* wd_pack = (u16*)d_ws;            // 557056 B
  u16* wu_pack = wd_pack + WD_ELEMS;    // +524288 B  (needs ~1.03 MB of ws)

  const int total = WD_ELEMS + WU_ELEMS;
  lora_prep<<<(total + 255) / 256, 256, 0, stream>>>(Wd, Wu, Wg, wd_pack, wu_pack);
  lora_main<<<M / ROWS, 512, LDS_TOTAL, stream>>>(x, bg, wd_pack, wu_pack, out);
}

// Round 11
// 53.719 us; speedup vs baseline: 1.6947x; 1.0444x over previous
//
#include <hip/hip_runtime.h>

typedef __attribute__((ext_vector_type(8))) short bf16x8;
typedef __attribute__((ext_vector_type(4))) float f32x4;
typedef unsigned short u16;

#define D_MODEL 1024
#define ROWS 32            // rows per block: grid 512, 2 blocks/CU, 8 waves each

// Packed-weight geometry: fragments of 512 bf16 (64 lanes x 8), frag(nt,kt).
// Phase-1 B: 17 col-tiles (16 down + 1 gate-padded) x 32 k-tiles (K=1024).
// Phase-2 B: 64 col-tiles (N=1024)                x  8 k-tiles (K=256).
#define WD_FRAGS (17 * 32)
#define WU_FRAGS (64 * 8)
#define WD_ELEMS (WD_FRAGS * 512)   // 278528 bf16
#define WU_ELEMS (WU_FRAGS * 512)   // 262144 bf16

// LDS map (bytes), total 49664:
//  phase 1: buf0 [0,16384) | buf1 [16384,32768)   (no g buffer — softmax in regs)
//  phase 2: ds (gated-down, 32x512B) = buf0 [0,16384)
//           tb (transpose, 32x260 f32 = 33280 B) = [16384,49664)  (buf1 dead)
#define LDS_TOTAL 49664
#define TB_STRIDE 260

__device__ __forceinline__ u16 f2bf(float f) {  // RNE f32 -> bf16
  union { float f; unsigned u; } v; v.f = f;
  return (u16)((v.u + 0x7fffu + ((v.u >> 16) & 1u)) >> 16);
}

// Pack per-expert weights into MFMA B-fragment order (bf16).
// Fragment element (lane, j) holds B[k = kt*32 + (lane>>4)*8 + j][col = nt*16 + (lane&15)].
__global__ void lora_prep(const float* __restrict__ Wd, const float* __restrict__ Wu,
                          const float* __restrict__ Wg,
                          u16* __restrict__ wd_pack, u16* __restrict__ wu_pack) {
  int idx = blockIdx.x * 256 + threadIdx.x;
  if (idx < WD_ELEMS) {
    int frag = idx >> 9, w = idx & 511;
    int lane = w >> 3, j = w & 7;
    int nt = frag >> 5, kt = frag & 31;
    int k = kt * 32 + (lane >> 4) * 8 + j;        // 0..1023
    int col = nt * 16 + (lane & 15);              // 0..271
    float v;
    if (col < 256) {
      v = Wd[((col >> 6) * 1024 + k) * 64 + (col & 63)];   // W_down[e][k][a]
    } else {
      int c2 = col - 256;
      v = (c2 < 4) ? Wg[k * 4 + c2] : 0.f;                 // W_gate[k][e], zero-padded
    }
    wd_pack[idx] = f2bf(v);
  } else if (idx < WD_ELEMS + WU_ELEMS) {
    int u = idx - WD_ELEMS;
    int frag = u >> 9, w = u & 511;
    int lane = w >> 3, j = w & 7;
    int nt = frag >> 3, kt = frag & 7;
    int k = kt * 32 + (lane >> 4) * 8 + j;        // 0..255 (= e*64 + a)
    int col = nt * 16 + (lane & 15);              // 0..1023
    wu_pack[u] = f2bf(Wu[((k >> 6) * 64 + (k & 63)) * 1024 + col]);  // W_up[e][a][d]
  }
}

// LDS chunk tile: [32 rows][256 k] bf16, row stride 512 B, XOR-swizzled:
// byte = row*512 + (2*k ^ ((row&7)<<4))  -> ds_read_b128 A-frags are ~2-way (free).
__device__ __forceinline__ void pack_store(char* dst, int r, int col, float4 v0, float4 v1) {
  bf16x8 h;
  h[0] = (short)f2bf(v0.x); h[1] = (short)f2bf(v0.y);
  h[2] = (short)f2bf(v0.z); h[3] = (short)f2bf(v0.w);
  h[4] = (short)f2bf(v1.x); h[5] = (short)f2bf(v1.y);
  h[6] = (short)f2bf(v1.z); h[7] = (short)f2bf(v1.w);
  int cb = col * 2;
  *(bf16x8*)(dst + r * 512 + (cb ^ ((r & 7) << 4))) = h;
}

__global__ __launch_bounds__(512, 4) void lora_main(
    const float* __restrict__ x, const float* __restrict__ b_gate,
    const u16* __restrict__ wd_pack, const u16* __restrict__ wu_pack,
    float* __restrict__ out) {
  extern __shared__ char smem[];

  const int tid = threadIdx.x;     // 0..511
  const int lane = tid & 63;
  const int wave = tid >> 6;       // 0..7
  const int l15 = lane & 15;
  const int lg = lane >> 4;
  const size_t row0 = (size_t)blockIdx.x * ROWS;
  const float* xblk = x + row0 * D_MODEL;

  f32x4 acc[2][2];   // [col-tile i][row-frag r]; wave w owns tiles {w, w+8}
  f32x4 accg[2];     // gate tile (nt=16) — ALL waves (identical), for in-reg softmax
#pragma unroll
  for (int i = 0; i < 2; ++i)
#pragma unroll
    for (int r = 0; r < 2; ++r) acc[i][r] = {0.f, 0.f, 0.f, 0.f};
#pragma unroll
  for (int r = 0; r < 2; ++r) accg[r] = {0.f, 0.f, 0.f, 0.f};

  // ---- prologue: stage K-chunk 0 into buf0 (fp32 -> bf16, swizzled)
#pragma unroll
  for (int it = 0; it < 2; ++it) {
    int flat = it * 4096 + tid * 8;          // 32 rows x 256 cols = 8192 floats
    int r = flat >> 8, col = flat & 255;
    float4 v0 = *(const float4*)(xblk + r * D_MODEL + col);
    float4 v1 = *(const float4*)(xblk + r * D_MODEL + col + 4);
    pack_store(smem, r, col, v0, v1);
  }
  __syncthreads();

  // ---- phase 1: down[32][256] + gate logits, K = 1024 in 4 chunks of 256.
  // R5-proven inner loop: bq/gq ring-3 depth-2 prefetch, a[] loaded in-loop.
  float4 pre[4];
  bf16x8 bq[3][2];
  bf16x8 gq[3];
#pragma unroll 1
  for (int c = 0; c < 4; ++c) {
    if (c < 3) {  // T14 split: issue next chunk's global loads before compute
      const float* src = xblk + (c + 1) * 256;
#pragma unroll
      for (int it = 0; it < 2; ++it) {
        int flat = it * 4096 + tid * 8;
        int r = flat >> 8, col = flat & 255;
        pre[2 * it]     = *(const float4*)(src + r * D_MODEL + col);
        pre[2 * it + 1] = *(const float4*)(src + r * D_MODEL + col + 4);
      }
    }
    const char* buf = smem + (c & 1) * 16384;
    // preload B for ks = 0,1
#pragma unroll
    for (int pk = 0; pk < 2; ++pk) {
      int ktg = c * 8 + pk;
#pragma unroll
      for (int i = 0; i < 2; ++i)
        bq[pk][i] = *(const bf16x8*)(wd_pack + (size_t)((wave + i * 8) * 32 + ktg) * 512 + lane * 8);
      gq[pk] = *(const bf16x8*)(wd_pack + (size_t)(512 + ktg) * 512 + lane * 8);
    }
#pragma unroll
    for (int ks = 0; ks < 8; ++ks) {
      const int s = ks % 3;
      if (ks < 6) {  // prefetch ks+2
        int ktg2 = c * 8 + ks + 2;
        int s2 = (ks + 2) % 3;
#pragma unroll
        for (int i = 0; i < 2; ++i)
          bq[s2][i] = *(const bf16x8*)(wd_pack + (size_t)((wave + i * 8) * 32 + ktg2) * 512 + lane * 8);
        gq[s2] = *(const bf16x8*)(wd_pack + (size_t)(512 + ktg2) * 512 + lane * 8);
      }
      bf16x8 a[2];
#pragma unroll
      for (int r = 0; r < 2; ++r) {
        int rr = r * 16 + l15;
        int cb = (ks * 32 + lg * 8) * 2;
        a[r] = *(const bf16x8*)(buf + rr * 512 + (cb ^ ((rr & 7) << 4)));
      }
      __builtin_amdgcn_s_setprio(1);           // T5: favor MFMA cluster
#pragma unroll
      for (int i = 0; i < 2; ++i)
#pragma unroll
        for (int r = 0; r < 2; ++r)
          acc[i][r] = __builtin_amdgcn_mfma_f32_16x16x32_bf16(a[r], bq[s][i], acc[i][r], 0, 0, 0);
#pragma unroll
      for (int r = 0; r < 2; ++r)
        accg[r] = __builtin_amdgcn_mfma_f32_16x16x32_bf16(a[r], gq[s], accg[r], 0, 0, 0);
      __builtin_amdgcn_s_setprio(0);
    }
    if (c < 3) {  // write-late: convert + ds_write into the other buffer
      char* dst = smem + ((c + 1) & 1) * 16384;
#pragma unroll
      for (int it = 0; it < 2; ++it) {
        int flat = it * 4096 + tid * 8;
        int r = flat >> 8, col = flat & 255;
        pack_store(dst, r, col, pre[2 * it], pre[2 * it + 1]);
      }
      __syncthreads();   // only needed between staging write and next chunk's reads
    }
  }
  // NOTE: no barrier after c=3 — softmax is in-register, pack writes buf0 (c=3 read buf1).

  // ---- gate softmax fully in registers.
  // accg C-layout: expert = l15 (valid 0..3; cols 4..15 are zero-pad), row = r*16+lg*4+j.
  // Butterfly over lane bits 0-1 (stays within the l15 nibble and same lg).
  float gown[2][4];
  {
    const float bg = b_gate[l15 & 3];
#pragma unroll
    for (int r = 0; r < 2; ++r)
#pragma unroll
      for (int j = 0; j < 4; ++j) {
        float v = accg[r][j] + bg;
        float m1 = fmaxf(v, __shfl_xor(v, 1));
        float mx = fmaxf(m1, __shfl_xor(m1, 2));
        float ex = expf(v - mx);
        float s1 = ex + __shfl_xor(ex, 1);
        float sm = s1 + __shfl_xor(s1, 2);
        gown[r][j] = ex / sm;    // this lane's expert (l15) weight for its rows
      }
  }

  // ---- apply gate, pack down to bf16 into buf0 (same swizzled layout, k=e*64+a).
  // Thread needs expert e=(wave+8i)>>2 weights for rows (lg,r,j): held by lane lg*16+e.
  char* ds = smem;
#pragma unroll
  for (int i = 0; i < 2; ++i) {
    int nt = wave + i * 8;
    int col = nt * 16 + l15;
    int e = nt >> 2;              // 4 col-tiles per expert
    int src = lg * 16 + e;
    int cb = col * 2;
#pragma unroll
    for (int r = 0; r < 2; ++r) {
#pragma unroll
      for (int j = 0; j < 4; ++j) {
        float gv = __shfl(gown[r][j], src);
        int row = r * 16 + lg * 4 + j;
        float val = acc[i][r][j] * gv;
        *(u16*)(ds + row * 512 + (cb ^ ((row & 7) << 4))) = f2bf(val);
      }
    }
  }
  __syncthreads();   // the single phase-1 -> phase-2 barrier

  // ---- phase 2: out[32][1024] = down_g[32][256] @ Wup, N in 4 chunks of 256.
  // Epilogue transposes through tb (aliases buf1, dead; DISJOINT from ds)
  // so each wave stores contiguous 1 KB float4 runs.
  float* tb = (float*)(smem + 16384);
  bf16x8 b2[3][2];
#pragma unroll 1
  for (int nc = 0; nc < 4; ++nc) {
    f32x4 acc2[2][2];
#pragma unroll
    for (int i = 0; i < 2; ++i)
#pragma unroll
      for (int r = 0; r < 2; ++r) acc2[i][r] = {0.f, 0.f, 0.f, 0.f};
    // preload B for ks = 0,1
#pragma unroll
    for (int pk = 0; pk < 2; ++pk)
#pragma unroll
      for (int i = 0; i < 2; ++i)
        b2[pk][i] = *(const bf16x8*)(wu_pack + (size_t)((nc * 16 + wave * 2 + i) * 8 + pk) * 512 + lane * 8);
#pragma unroll
    for (int ks = 0; ks < 8; ++ks) {
      const int s = ks % 3;
      if (ks < 6) {  // prefetch ks+2
        int s2 = (ks + 2) % 3;
#pragma unroll
        for (int i = 0; i < 2; ++i)
          b2[s2][i] = *(const bf16x8*)(wu_pack + (size_t)((nc * 16 + wave * 2 + i) * 8 + ks + 2) * 512 + lane * 8);
      }
      bf16x8 a[2];
#pragma unroll
      for (int r = 0; r < 2; ++r) {
        int rr = r * 16 + l15;
        int cb = (ks * 32 + lg * 8) * 2;
        a[r] = *(const bf16x8*)(ds + rr * 512 + (cb ^ ((rr & 7) << 4)));
      }
      __builtin_amdgcn_s_setprio(1);
#pragma unroll
      for (int i = 0; i < 2; ++i)
#pragma unroll
        for (int r = 0; r < 2; ++r)
          acc2[i][r] = __builtin_amdgcn_mfma_f32_16x16x32_bf16(a[r], b2[s][i], acc2[i][r], 0, 0, 0);
      __builtin_amdgcn_s_setprio(0);
    }
#pragma unroll
    for (int i = 0; i < 2; ++i) {
      int cl = wave * 32 + i * 16 + l15;    // col within this 256-col chunk
#pragma unroll
      for (int r = 0; r < 2; ++r)
#pragma unroll
        for (int j = 0; j < 4; ++j)
          tb[(r * 16 + lg * 4 + j) * TB_STRIDE + cl] = acc2[i][r][j];
    }
    __syncthreads();
#pragma unroll
    for (int it = 0; it < 4; ++it) {
      int flat = it * 2048 + tid * 4;       // 32 rows x 256 cols f32
      int row = flat >> 8, col = flat & 255;
      float4 v = *(const float4*)(tb + row * TB_STRIDE + col);
      *(float4*)(out + (row0 + row) * D_MODEL + nc * 256 + col) = v;
    }
    __syncthreads();
  }
}

extern "C" void kernel_launch(void* const* d_in, const int* in_sizes, int n_in,
                              void* d_out, int out_size, void* d_ws, size_t ws_size,
                              hipStream_t stream) {
  const float* x  = (const float*)d_in[0];
  const float* Wd = (const float*)d_in[1];
  const float* Wu = (const float*)d_in[2];
  const float* Wg = (const float*)d_in[3];
  const float* bg = (const float*)d_in[4];
  float* out = (float*)d_out;
  const int M = in_sizes[0] / D_MODEL;  // 16384

  u16* wd_pack = (u16*)d_ws;            // 557056 B
  u16* wu_pack = wd_pack + WD_ELEMS;    // +524288 B  (needs ~1.03 MB of ws)

  const int total = WD_ELEMS + WU_ELEMS;
  lora_prep<<<(total + 255) / 256, 256, 0, stream>>>(Wd, Wu, Wg, wd_pack, wu_pack);
  lora_main<<<M / ROWS, 512, LDS_TOTAL, stream>>>(x, bg, wd_pack, wu_pack, out);
}